// Round 7
// baseline (15045.132 us; speedup 1.0000x reference)
//
#include <hip/hip_runtime.h>
#include <stdint.h>

#define T_ 1024

typedef float  floatx4 __attribute__((ext_vector_type(4)));
typedef short  shortx8 __attribute__((ext_vector_type(8)));
typedef unsigned long long u64;

union U16 { u64 q[2]; unsigned d[4]; shortx8 v; };

__device__ __forceinline__ unsigned short f2bf(float f) {
  union { float f; unsigned u; } v; v.f = f;
  return (unsigned short)((v.u + 0x7FFFu + ((v.u >> 16) & 1u)) >> 16);
}
__device__ __forceinline__ float bf2f(unsigned h) {
  union { unsigned u; float f; } v; v.u = h << 16; return v.f;
}
__device__ __forceinline__ unsigned pkbf(float lo, float hi) {
  unsigned r;
  asm("v_cvt_pk_bf16_f32 %0, %1, %2" : "=v"(r) : "v"(lo), "v"(hi));
  return r;
}
__device__ __forceinline__ u64 lda(const u64* p) {
  return __hip_atomic_load(p, __ATOMIC_RELAXED, __HIP_MEMORY_SCOPE_AGENT);
}
__device__ __forceinline__ void sta(u64* p, u64 v) {
  __hip_atomic_store(p, v, __ATOMIC_RELAXED, __HIP_MEMORY_SCOPE_AGENT);
}

// ---- prep: poison y0buf (32 MB) and dout (67 MB) with NaN sentinel ----
__global__ void prep_kernel(uint4* __restrict__ y0buf, uint4* __restrict__ doutp) {
  long gid = (long)blockIdx.x * 256 + threadIdx.x;
  uint4 P; P.x = P.y = P.z = P.w = 0xFFFFFFFFu;
  if (gid < 2097152L) y0buf[gid] = P;
  else {
    long z = gid - 2097152L;
    if (z < 4202496L) doutp[z] = P;
  }
}

// ---- single-wave GRU block: full-K, in-register gates, sentinel exchange ----
template<int L>
__device__ __forceinline__ void gru_wave(int lb, int l,
    const float* __restrict__ x,
    const float* __restrict__ whh, const float* __restrict__ wih,
    const float* __restrict__ bih, const float* __restrict__ bhh,
    u64* __restrict__ y0buf, float* __restrict__ dout,
    short* __restrict__ wlds, unsigned short (*tile)[16])
{
  constexpr int KW = L ? 2048 : 1280;   // K = [h(1024) | x(1024 or 256)]
  constexpr int WS = KW + 8;            // padded LDS row stride (shorts)
  constexpr int NC = L ? 8 : 16;        // cols per block
  constexpr int NR = 3 * NC;
  constexpr int KX = L ? 1024 : 256;    // wih inner dim
  const int cb = lb * NC;
  const int lr = l & 15, lq = l >> 4;
  const int c  = L ? (lr & 7) : lr;

  // ---- one-time: stage weights fp32 -> bf16 LDS ----
  for (int i = l; i < NR * (KW / 4); i += 64) {
    int row = i / (KW / 4);
    int k   = (i % (KW / 4)) * 4;
    int g = row / NC, cc = row % NC;
    const float* src = (k < 1024) ? (whh + (long)(g * 1024 + cb + cc) * 1024 + k)
                                  : (wih + (long)(g * 1024 + cb + cc) * KX + (k - 1024));
    float4 v = *(const float4*)src;
    uint2 t2; t2.x = pkbf(v.x, v.y); t2.y = pkbf(v.z, v.w);
    *(uint2*)(wlds + row * WS + k) = t2;
  }
  const float bir = bih[cb + c], biz = bih[1024 + cb + c], bin = bih[2048 + cb + c];
  const float bhr = bhh[cb + c], bhz = bhh[1024 + cb + c], bhn = bhh[2048 + cb + c];
  __syncthreads();

  const short* w0 = wlds + (0 * NC + c) * WS;
  const short* w1 = wlds + (1 * NC + c) * WS;
  const short* w2 = wlds + (2 * NC + c) * WS;

  floatx4 hp = {0.f, 0.f, 0.f, 0.f};

  for (int t = 0; t < T_; ++t) {
    floatx4 ar = {0.f, 0.f, 0.f, 0.f};
    floatx4 az = ar, anh = ar, anx = ar;

    // ---- ready-data part first (hides own-chain publish latency) ----
    if constexpr (L == 0) {
      // x-part: 8 k-tiles, plain cached loads + cvt
#pragma unroll
      for (int kt = 0; kt < 8; ++kt) {
        const float* xs = x + ((long)lr * T_ + t) * 256 + kt * 32 + lq * 8;
        float4 a = *(const float4*)xs;
        float4 b = *(const float4*)(xs + 4);
        U16 u;
        u.d[0] = pkbf(a.x, a.y); u.d[1] = pkbf(a.z, a.w);
        u.d[2] = pkbf(b.x, b.y); u.d[3] = pkbf(b.z, b.w);
        const int ko = 1024 + kt * 32 + lq * 8;
        ar  = __builtin_amdgcn_mfma_f32_16x16x32_bf16(u.v, *(const shortx8*)(w0 + ko), ar,  0, 0, 0);
        az  = __builtin_amdgcn_mfma_f32_16x16x32_bf16(u.v, *(const shortx8*)(w1 + ko), az,  0, 0, 0);
        anx = __builtin_amdgcn_mfma_f32_16x16x32_bf16(u.v, *(const shortx8*)(w2 + ko), anx, 0, 0, 0);
      }
    } else {
      // y0-part: poll+consume y0buf[t] in 4 chunks of 8 k-tiles
      const u64* base = y0buf + (((long)t * 16 + lr) * 1024 >> 2);
      for (int ch = 0; ch < 4; ++ch) {
        u64 q[16];
        for (;;) {
          bool ok = true;
#pragma unroll
          for (int j = 0; j < 8; ++j) {
            const int ck = (ch * 8 + j) * 32 + lq * 8;
            q[2 * j]     = lda(base + (ck >> 2));
            q[2 * j + 1] = lda(base + (ck >> 2) + 1);
          }
#pragma unroll
          for (int j = 0; j < 16; ++j) ok &= (q[j] != ~0ull);
          if (__all(ok)) break;
        }
#pragma unroll
        for (int j = 0; j < 8; ++j) {
          const int kt = ch * 8 + j;
          const int ko = 1024 + kt * 32 + lq * 8;
          U16 u; u.q[0] = q[2 * j]; u.q[1] = q[2 * j + 1];
          ar  = __builtin_amdgcn_mfma_f32_16x16x32_bf16(u.v, *(const shortx8*)(w0 + ko), ar,  0, 0, 0);
          az  = __builtin_amdgcn_mfma_f32_16x16x32_bf16(u.v, *(const shortx8*)(w1 + ko), az,  0, 0, 0);
          anx = __builtin_amdgcn_mfma_f32_16x16x32_bf16(u.v, *(const shortx8*)(w2 + ko), anx, 0, 0, 0);
        }
      }
    }

    // ---- h-part (tight chain) ----
    if (t > 0) {
      if constexpr (L == 0) {
        // h = y0[t-1] (bf16 pieces), 4 chunks of 8 k-tiles
        const u64* base = y0buf + (((long)(t - 1) * 16 + lr) * 1024 >> 2);
        for (int ch = 0; ch < 4; ++ch) {
          u64 q[16];
          for (;;) {
            bool ok = true;
#pragma unroll
            for (int j = 0; j < 8; ++j) {
              const int ck = (ch * 8 + j) * 32 + lq * 8;
              q[2 * j]     = lda(base + (ck >> 2));
              q[2 * j + 1] = lda(base + (ck >> 2) + 1);
            }
#pragma unroll
            for (int j = 0; j < 16; ++j) ok &= (q[j] != ~0ull);
            if (__all(ok)) break;
          }
#pragma unroll
          for (int j = 0; j < 8; ++j) {
            const int ko = (ch * 8 + j) * 32 + lq * 8;
            U16 u; u.q[0] = q[2 * j]; u.q[1] = q[2 * j + 1];
            ar  = __builtin_amdgcn_mfma_f32_16x16x32_bf16(u.v, *(const shortx8*)(w0 + ko), ar,  0, 0, 0);
            az  = __builtin_amdgcn_mfma_f32_16x16x32_bf16(u.v, *(const shortx8*)(w1 + ko), az,  0, 0, 0);
            anh = __builtin_amdgcn_mfma_f32_16x16x32_bf16(u.v, *(const shortx8*)(w2 + ko), anh, 0, 0, 0);
          }
        }
      } else {
        // h = y[t-1] read from dout (fp32), 8 chunks of 4 k-tiles
        const u64* base = (const u64*)dout + (((long)lr * 1048576 + (long)(t - 1) * 1024) >> 1);
        for (int ch = 0; ch < 8; ++ch) {
          u64 q[16];
          for (;;) {
            bool ok = true;
#pragma unroll
            for (int j = 0; j < 4; ++j) {
              const int ck = (ch * 4 + j) * 32 + lq * 8;
#pragma unroll
              for (int i2 = 0; i2 < 4; ++i2)
                q[4 * j + i2] = lda(base + (ck >> 1) + i2);
            }
#pragma unroll
            for (int j = 0; j < 16; ++j) ok &= (q[j] != ~0ull);
            if (__all(ok)) break;
          }
#pragma unroll
          for (int j = 0; j < 4; ++j) {
            const int ko = (ch * 4 + j) * 32 + lq * 8;
            float f0 = __uint_as_float((unsigned)q[4 * j + 0]);
            float f1 = __uint_as_float((unsigned)(q[4 * j + 0] >> 32));
            float f2 = __uint_as_float((unsigned)q[4 * j + 1]);
            float f3 = __uint_as_float((unsigned)(q[4 * j + 1] >> 32));
            float f4 = __uint_as_float((unsigned)q[4 * j + 2]);
            float f5 = __uint_as_float((unsigned)(q[4 * j + 2] >> 32));
            float f6 = __uint_as_float((unsigned)q[4 * j + 3]);
            float f7 = __uint_as_float((unsigned)(q[4 * j + 3] >> 32));
            U16 u;
            u.d[0] = pkbf(f0, f1); u.d[1] = pkbf(f2, f3);
            u.d[2] = pkbf(f4, f5); u.d[3] = pkbf(f6, f7);
            ar  = __builtin_amdgcn_mfma_f32_16x16x32_bf16(u.v, *(const shortx8*)(w0 + ko), ar,  0, 0, 0);
            az  = __builtin_amdgcn_mfma_f32_16x16x32_bf16(u.v, *(const shortx8*)(w1 + ko), az,  0, 0, 0);
            anh = __builtin_amdgcn_mfma_f32_16x16x32_bf16(u.v, *(const shortx8*)(w2 + ko), anh, 0, 0, 0);
          }
        }
      }
    }

    // ---- gates fully in-register (lane holds (batch, col) = C/D layout) ----
    floatx4 hn;
#pragma unroll
    for (int r4 = 0; r4 < 4; ++r4) {
      float rg = 1.f / (1.f + __expf(-(ar[r4] + bir + bhr)));
      float zg = 1.f / (1.f + __expf(-(az[r4] + biz + bhz)));
      float tg = anx[r4] + bin + rg * (anh[r4] + bhn);
      float e2 = __expf(2.f * tg);
      float ng = 1.f - 2.f / (e2 + 1.f);
      hn[r4] = (1.f - zg) * ng + zg * hp[r4];
    }
    hp = hn;

    // ---- gather to LDS tile (batch-major pieces), then publish ----
#pragma unroll
    for (int r4 = 0; r4 < 4; ++r4)
      tile[lq * 4 + r4][lr] = f2bf(hn[r4]);
    asm volatile("s_waitcnt lgkmcnt(0)" ::: "memory");
    __builtin_amdgcn_sched_barrier(0);

    if constexpr (L == 0) {
      if (l < 32) {
        const int b = l & 15, hf = l >> 4;
        uint4 d = *(const uint4*)&tile[b][hf * 8];
        u64* dst = y0buf + ((((long)t * 16 + b) * 1024 + cb + hf * 8) >> 2);
        sta(dst,     ((u64)d.y << 32) | d.x);
        sta(dst + 1, ((u64)d.w << 32) | d.z);
      }
    } else {
      if (l < 16) {
        const int b = l;
        uint4 d = *(const uint4*)&tile[b][0];
        float f0 = bf2f(d.x & 0xffff), f1 = bf2f(d.x >> 16);
        float f2 = bf2f(d.y & 0xffff), f3 = bf2f(d.y >> 16);
        float f4 = bf2f(d.z & 0xffff), f5 = bf2f(d.z >> 16);
        float f6 = bf2f(d.w & 0xffff), f7 = bf2f(d.w >> 16);
        u64* dst = (u64*)dout + (((long)b * 1048576 + (long)t * 1024 + cb) >> 1);
        sta(dst + 0, ((u64)__float_as_uint(f1) << 32) | __float_as_uint(f0));
        sta(dst + 1, ((u64)__float_as_uint(f3) << 32) | __float_as_uint(f2));
        sta(dst + 2, ((u64)__float_as_uint(f5) << 32) | __float_as_uint(f4));
        sta(dst + 3, ((u64)__float_as_uint(f7) << 32) | __float_as_uint(f6));
      }
    }

    if (t == T_ - 1 && l < 16) {
      const int b = l;
      float* dst = dout + 16777216L + (L ? 16384 : 0) + (long)b * 1024 + cb;
#pragma unroll
      for (int j = 0; j < NC; ++j) dst[j] = bf2f(tile[b][j]);
    }
    asm volatile("s_waitcnt lgkmcnt(0)" ::: "memory");
  }
}

__global__ __launch_bounds__(64, 1) void gru_kernel(
    const float* __restrict__ x,
    const float* __restrict__ whh0, const float* __restrict__ wih0,
    const float* __restrict__ bih0, const float* __restrict__ bhh0,
    const float* __restrict__ whh1, const float* __restrict__ wih1,
    const float* __restrict__ bih1, const float* __restrict__ bhh1,
    u64* y0buf, float* dout)
{
  __shared__ __align__(16) short wlds[48 * 1288];        // 123,648 B (L1 uses 24*2056 subset)
  __shared__ __align__(16) unsigned short tile[16][16];  // 512 B
  const int bid = blockIdx.x, tid = threadIdx.x;
  if (bid < 64)
    gru_wave<0>(bid, tid, x, whh0, wih0, bih0, bhh0, y0buf, dout, wlds, tile);
  else
    gru_wave<1>(bid - 64, tid, x, whh1, wih1, bih1, bhh1, y0buf, dout, wlds, tile);
}

extern "C" void kernel_launch(void* const* d_in, const int* in_sizes, int n_in,
                              void* d_out, int out_size, void* d_ws, size_t ws_size,
                              hipStream_t stream) {
  (void)in_sizes; (void)n_in; (void)out_size; (void)ws_size;
  const float* x    = (const float*)d_in[0];
  const float* wih0 = (const float*)d_in[2];
  const float* whh0 = (const float*)d_in[3];
  const float* bih0 = (const float*)d_in[4];
  const float* bhh0 = (const float*)d_in[5];
  const float* wih1 = (const float*)d_in[6];
  const float* whh1 = (const float*)d_in[7];
  const float* bih1 = (const float*)d_in[8];
  const float* bhh1 = (const float*)d_in[9];
  u64*   y0buf = (u64*)d_ws;          // 33,554,432 B, NaN-poisoned each call
  float* out   = (float*)d_out;       // poisoned each call, fully rewritten

  prep_kernel<<<24608, 256, 0, stream>>>((uint4*)y0buf, (uint4*)out);
  gru_kernel<<<192, 64, 0, stream>>>(x, whh0, wih0, bih0, bhh0,
                                     whh1, wih1, bih1, bhh1, y0buf, out);
}

// Round 8
// 8894.305 us; speedup vs baseline: 1.6915x; 1.6915x over previous
//
#include <hip/hip_runtime.h>
#include <stdint.h>

#define T_ 1024

typedef float  floatx4 __attribute__((ext_vector_type(4)));
typedef short  shortx8 __attribute__((ext_vector_type(8)));
typedef unsigned long long u64;

union U16 { u64 q[2]; unsigned d[4]; shortx8 v; };

__device__ __forceinline__ unsigned short f2bf(float f) {
  union { float f; unsigned u; } v; v.f = f;
  return (unsigned short)((v.u + 0x7FFFu + ((v.u >> 16) & 1u)) >> 16);
}
__device__ __forceinline__ unsigned pkbf(float lo, float hi) {
  unsigned r;
  asm("v_cvt_pk_bf16_f32 %0, %1, %2" : "=v"(r) : "v"(lo), "v"(hi));
  return r;
}
__device__ __forceinline__ u64 lda(const u64* p) {
  return __hip_atomic_load(p, __ATOMIC_RELAXED, __HIP_MEMORY_SCOPE_AGENT);
}
__device__ __forceinline__ void sta(u64* p, u64 v) {
  __hip_atomic_store(p, v, __ATOMIC_RELAXED, __HIP_MEMORY_SCOPE_AGENT);
}

// ---- prep: poison y0buf (32 MB) and dout (67 MB) with NaN sentinel ----
__global__ void prep_kernel(uint4* __restrict__ y0buf, uint4* __restrict__ doutp) {
  long gid = (long)blockIdx.x * 256 + threadIdx.x;
  uint4 P; P.x = P.y = P.z = P.w = 0xFFFFFFFFu;
  if (gid < 2097152L) y0buf[gid] = P;
  else {
    long z = gid - 2097152L;
    if (z < 4202496L) doutp[z] = P;
  }
}

#define MFMA __builtin_amdgcn_mfma_f32_16x16x32_bf16

// ---- persistent GRU: sentinel exchange, 4-wave K-split blocks ----
template<int L>
__device__ __forceinline__ void gru_wave(int lb, int tid,
    const float* __restrict__ x,
    const float* __restrict__ whh, const float* __restrict__ wih,
    const float* __restrict__ bih, const float* __restrict__ bhh,
    u64* __restrict__ y0buf, float* __restrict__ dout,
    short* __restrict__ wlds, float (*part)[4][4][16][17])
{
  constexpr int KW  = L ? 2048 : 1280;  // K = [h(1024) | x(1024 or 256)]
  constexpr int WS  = KW + 8;           // padded LDS row stride (shorts)
  constexpr int NC  = L ? 8 : 16;       // cols per block
  constexpr int NR  = 3 * NC;
  constexpr int KXs = L ? 1024 : 256;   // wih inner stride
  const int cb = lb * NC;
  const int w  = tid >> 6;
  const int l  = tid & 63;
  const int lr = l & 15, lq = l >> 4;
  const int c  = L ? (lr & 7) : lr;

  // ---- one-time: stage weights fp32 -> bf16 LDS ----
  for (int i = tid; i < NR * (KW / 8); i += 256) {
    int row = i / (KW / 8);
    int k   = (i % (KW / 8)) * 8;
    int g = row / NC, cc = row % NC;
    const float* src = (k < 1024) ? (whh + (long)(g * 1024 + cb + cc) * 1024 + k)
                                  : (wih + (long)(g * 1024 + cb + cc) * KXs + (k - 1024));
    float4 a = *(const float4*)src;
    float4 b = *(const float4*)(src + 4);
    uint4 t4;
    t4.x = pkbf(a.x, a.y); t4.y = pkbf(a.z, a.w);
    t4.z = pkbf(b.x, b.y); t4.w = pkbf(b.z, b.w);
    *(uint4*)(wlds + row * WS + k) = t4;
  }

  const int gb = tid >> (L ? 3 : 4);
  const int gc = tid & (NC - 1);
  const bool isg = tid < 16 * NC;
  float bir = 0, biz = 0, bin = 0, bhr = 0, bhz = 0, bhn = 0;
  if (isg) {
    bir = bih[cb + gc];        bhr = bhh[cb + gc];
    biz = bih[1024 + cb + gc]; bhz = bhh[1024 + cb + gc];
    bin = bih[2048 + cb + gc]; bhn = bhh[2048 + cb + gc];
  }
  __syncthreads();

  const short* w0 = wlds + (0 * NC + c) * WS;
  const short* w1 = wlds + (1 * NC + c) * WS;
  const short* w2 = wlds + (2 * NC + c) * WS;

  float hp = 0.f;

  for (int t = 0; t < T_; ++t) {
    floatx4 ar = {0.f, 0.f, 0.f, 0.f};
    floatx4 az = ar, anh = ar, anx = ar;

    if constexpr (L == 0) {
      // ---- x-part first (always ready; hides publish->visible latency) ----
#pragma unroll
      for (int j = 0; j < 2; ++j) {
        const int kt = w * 2 + j;
        const float* xs = x + (long)lr * 262144 + (long)t * 256 + kt * 32 + lq * 8;
        float4 a = *(const float4*)xs;
        float4 b = *(const float4*)(xs + 4);
        U16 u;
        u.d[0] = pkbf(a.x, a.y); u.d[1] = pkbf(a.z, a.w);
        u.d[2] = pkbf(b.x, b.y); u.d[3] = pkbf(b.z, b.w);
        const int ko = 1024 + kt * 32 + lq * 8;
        ar  = MFMA(u.v, *(const shortx8*)(w0 + ko), ar,  0, 0, 0);
        az  = MFMA(u.v, *(const shortx8*)(w1 + ko), az,  0, 0, 0);
        anx = MFMA(u.v, *(const shortx8*)(w2 + ko), anx, 0, 0, 0);
      }
      // ---- one-shot sentinel poll of own K-slice of h0[t-1] ----
      if (t > 0) {
        const u64* base = y0buf + ((long)(t - 1) * 16 + lr) * 256 + w * 64 + lq * 2;
        u64 q[16];
        for (;;) {
          bool ok = true;
#pragma unroll
          for (int j = 0; j < 8; ++j) {
            q[2 * j]     = lda(base + j * 8);
            q[2 * j + 1] = lda(base + j * 8 + 1);
          }
#pragma unroll
          for (int j = 0; j < 16; ++j) ok &= (q[j] != ~0ull);
          if (__all(ok)) break;
        }
#pragma unroll
        for (int j = 0; j < 8; ++j) {
          U16 u; u.q[0] = q[2 * j]; u.q[1] = q[2 * j + 1];
          const int ko = (w * 8 + j) * 32 + lq * 8;
          ar  = MFMA(u.v, *(const shortx8*)(w0 + ko), ar,  0, 0, 0);
          az  = MFMA(u.v, *(const shortx8*)(w1 + ko), az,  0, 0, 0);
          anh = MFMA(u.v, *(const shortx8*)(w2 + ko), anh, 0, 0, 0);
        }
      }
    } else {
      // ---- merged one-shot poll: y0[t] (bf16) + h1[t-1] (fp32 from dout) ----
      const u64* yb = y0buf + ((long)t * 16 + lr) * 256 + w * 64 + lq * 2;
      const u64* hb = (const u64*)dout + (((long)lr * 1048576 + (long)(t - 1) * 1024) >> 1)
                      + w * 128 + lq * 4;
      u64 qy[16], qh[32];
      for (;;) {
        bool ok = true;
#pragma unroll
        for (int j = 0; j < 8; ++j) {
          qy[2 * j]     = lda(yb + j * 8);
          qy[2 * j + 1] = lda(yb + j * 8 + 1);
        }
#pragma unroll
        for (int j = 0; j < 16; ++j) ok &= (qy[j] != ~0ull);
        if (t > 0) {
#pragma unroll
          for (int j = 0; j < 8; ++j) {
#pragma unroll
            for (int i2 = 0; i2 < 4; ++i2)
              qh[4 * j + i2] = lda(hb + j * 16 + i2);
          }
#pragma unroll
          for (int j = 0; j < 32; ++j) ok &= (qh[j] != ~0ull);
        }
        if (__all(ok)) break;
      }
#pragma unroll
      for (int j = 0; j < 8; ++j) {
        U16 u; u.q[0] = qy[2 * j]; u.q[1] = qy[2 * j + 1];
        const int ko = 1024 + (w * 8 + j) * 32 + lq * 8;
        ar  = MFMA(u.v, *(const shortx8*)(w0 + ko), ar,  0, 0, 0);
        az  = MFMA(u.v, *(const shortx8*)(w1 + ko), az,  0, 0, 0);
        anx = MFMA(u.v, *(const shortx8*)(w2 + ko), anx, 0, 0, 0);
      }
      if (t > 0) {
#pragma unroll
        for (int j = 0; j < 8; ++j) {
          U16 u;
#pragma unroll
          for (int i2 = 0; i2 < 4; ++i2) {
            u64 p = qh[4 * j + i2];
            u.d[i2] = pkbf(__uint_as_float((unsigned)p),
                           __uint_as_float((unsigned)(p >> 32)));
          }
          const int ko = (w * 8 + j) * 32 + lq * 8;
          ar  = MFMA(u.v, *(const shortx8*)(w0 + ko), ar,  0, 0, 0);
          az  = MFMA(u.v, *(const shortx8*)(w1 + ko), az,  0, 0, 0);
          anh = MFMA(u.v, *(const shortx8*)(w2 + ko), anh, 0, 0, 0);
        }
      }
    }

    // ---- cross-wave combine (double-buffered partials, one barrier) ----
    const int par = t & 1;
    if (L == 0 || lr < 8) {
#pragma unroll
      for (int r4 = 0; r4 < 4; ++r4) {
        const int b = lq * 4 + r4;          // row = batch (m89 C/D layout)
        part[par][w][0][b][lr] = ar[r4];
        part[par][w][1][b][lr] = az[r4];
        part[par][w][2][b][lr] = anh[r4];
        part[par][w][3][b][lr] = anx[r4];
      }
    }
    __syncthreads();

    if (isg) {
      float sr = 0, sz = 0, snh = 0, snx = 0;
#pragma unroll
      for (int ww = 0; ww < 4; ++ww) {
        sr  += part[par][ww][0][gb][gc];
        sz  += part[par][ww][1][gb][gc];
        snh += part[par][ww][2][gb][gc];
        snx += part[par][ww][3][gb][gc];
      }
      float r = 1.f / (1.f + __expf(-(sr + bir + bhr)));
      float z = 1.f / (1.f + __expf(-(sz + biz + bhz)));
      float targ = snx + bin + r * (snh + bhn);
      float e2 = __expf(2.f * targ);
      float n = 1.f - 2.f / (e2 + 1.f);       // tanh
      float hn = (1.f - z) * n + z * hp;
      hp = hn;

      // ---- publish (fire-and-forget 8B agent stores; data IS the flag) ----
      if constexpr (L == 0) {
        unsigned hv = f2bf(hn);
        unsigned v1 = (unsigned)__shfl_down((int)hv, 1);
        unsigned v2 = (unsigned)__shfl_down((int)hv, 2);
        unsigned v3 = (unsigned)__shfl_down((int)hv, 3);
        if ((gc & 3) == 0) {
          u64 word = (u64)(hv | (v1 << 16)) | ((u64)(v2 | (v3 << 16)) << 32);
          sta(y0buf + ((long)t * 16 + gb) * 256 + ((cb + gc) >> 2), word);
        }
        if (t == T_ - 1) dout[16777216L + (long)gb * 1024 + cb + gc] = hn;
      } else {
        unsigned f0 = __float_as_uint(hn);
        unsigned f1 = (unsigned)__shfl_down((int)f0, 1);
        if ((gc & 1) == 0)
          sta((u64*)dout + (((long)gb * 1048576 + (long)t * 1024 + cb + gc) >> 1),
              (u64)f0 | ((u64)f1 << 32));
        if (t == T_ - 1) dout[16777216L + 16384 + (long)gb * 1024 + cb + gc] = hn;
      }
    }
  }
}

__global__ __launch_bounds__(256, 1) void gru_kernel(
    const float* __restrict__ x,
    const float* __restrict__ whh0, const float* __restrict__ wih0,
    const float* __restrict__ bih0, const float* __restrict__ bhh0,
    const float* __restrict__ whh1, const float* __restrict__ wih1,
    const float* __restrict__ bih1, const float* __restrict__ bhh1,
    u64* y0buf, float* dout)
{
  __shared__ __align__(16) short wlds[48 * 1288];       // 123,648 B (L1 uses 24*2056)
  __shared__ float part[2][4][4][16][17];               //  34,816 B
  const int bid = blockIdx.x, tid = threadIdx.x;
  if (bid < 64)
    gru_wave<0>(bid, tid, x, whh0, wih0, bih0, bhh0, y0buf, dout, wlds, part);
  else
    gru_wave<1>(bid - 64, tid, x, whh1, wih1, bih1, bhh1, y0buf, dout, wlds, part);
}

extern "C" void kernel_launch(void* const* d_in, const int* in_sizes, int n_in,
                              void* d_out, int out_size, void* d_ws, size_t ws_size,
                              hipStream_t stream) {
  (void)in_sizes; (void)n_in; (void)out_size; (void)ws_size;
  const float* x    = (const float*)d_in[0];
  const float* wih0 = (const float*)d_in[2];
  const float* whh0 = (const float*)d_in[3];
  const float* bih0 = (const float*)d_in[4];
  const float* bhh0 = (const float*)d_in[5];
  const float* wih1 = (const float*)d_in[6];
  const float* whh1 = (const float*)d_in[7];
  const float* bih1 = (const float*)d_in[8];
  const float* bhh1 = (const float*)d_in[9];
  u64*   y0buf = (u64*)d_ws;          // 33,554,432 B, NaN-poisoned each call
  float* out   = (float*)d_out;       // NaN-poisoned each call, fully rewritten

  prep_kernel<<<24608, 256, 0, stream>>>((uint4*)y0buf, (uint4*)out);
  gru_kernel<<<192, 256, 0, stream>>>(x, whh0, wih0, bih0, bhh0,
                                      whh1, wih1, bih1, bhh1, y0buf, out);
}

// Round 9
// 6362.392 us; speedup vs baseline: 2.3647x; 1.3979x over previous
//
#include <hip/hip_runtime.h>
#include <stdint.h>

#define T_ 1024

typedef float  floatx4 __attribute__((ext_vector_type(4)));
typedef short  shortx8 __attribute__((ext_vector_type(8)));
typedef unsigned long long u64;

union U16 { u64 q[2]; unsigned d[4]; shortx8 v; };

__device__ __forceinline__ unsigned short f2bf(float f) {
  union { float f; unsigned u; } v; v.f = f;
  return (unsigned short)((v.u + 0x7FFFu + ((v.u >> 16) & 1u)) >> 16);
}
__device__ __forceinline__ unsigned pkbf(float lo, float hi) {
  unsigned r;
  asm("v_cvt_pk_bf16_f32 %0, %1, %2" : "=v"(r) : "v"(lo), "v"(hi));
  return r;
}
__device__ __forceinline__ u64 lda(const u64* p) {
  return __hip_atomic_load(p, __ATOMIC_RELAXED, __HIP_MEMORY_SCOPE_AGENT);
}
__device__ __forceinline__ void sta(u64* p, u64 v) {
  __hip_atomic_store(p, v, __ATOMIC_RELAXED, __HIP_MEMORY_SCOPE_AGENT);
}

// ---- prep: zero the write-once flag arrays (12 MB) ----
__global__ void prep_kernel(uint4* __restrict__ fz) {
  long gid = (long)blockIdx.x * 256 + threadIdx.x;
  if (gid < 786432L) { uint4 z; z.x = z.y = z.z = z.w = 0u; fz[gid] = z; }
}

#define MFMA __builtin_amdgcn_mfma_f32_16x16x32_bf16

// ---- persistent GRU: thin write-once flags, read-once data, 4-wave K-split ----
template<int L>
__device__ __forceinline__ void gru_wave(int lb, int tid,
    const float* __restrict__ x,
    const float* __restrict__ whh, const float* __restrict__ wih,
    const float* __restrict__ bih, const float* __restrict__ bhh,
    u64* __restrict__ y0buf, u64* __restrict__ h1ring,
    u64* __restrict__ f0, u64* __restrict__ f1,
    float* __restrict__ dout,
    short* __restrict__ wlds, float (*part)[4][4][16][17])
{
  constexpr int KW  = L ? 2048 : 1280;  // K = [h(1024) | x(1024 or 256)]
  constexpr int WS  = KW + 8;           // padded LDS row stride (shorts)
  constexpr int NC  = L ? 8 : 16;       // cols per block
  constexpr int NR  = 3 * NC;
  constexpr int KXs = L ? 1024 : 256;   // wih inner stride
  const int cb = lb * NC;
  const int w  = tid >> 6;
  const int l  = tid & 63;
  const int lr = l & 15, lq = l >> 4;
  const int c  = L ? (lr & 7) : lr;

  // ---- one-time: stage weights fp32 -> bf16 LDS ----
  for (int i = tid; i < NR * (KW / 8); i += 256) {
    int row = i / (KW / 8);
    int k   = (i % (KW / 8)) * 8;
    int g = row / NC, cc = row % NC;
    const float* src = (k < 1024) ? (whh + (long)(g * 1024 + cb + cc) * 1024 + k)
                                  : (wih + (long)(g * 1024 + cb + cc) * KXs + (k - 1024));
    float4 a = *(const float4*)src;
    float4 b = *(const float4*)(src + 4);
    uint4 t4;
    t4.x = pkbf(a.x, a.y); t4.y = pkbf(a.z, a.w);
    t4.z = pkbf(b.x, b.y); t4.w = pkbf(b.z, b.w);
    *(uint4*)(wlds + row * WS + k) = t4;
  }

  const int gb = tid >> (L ? 3 : 4);
  const int gc = tid & (NC - 1);
  const bool isg = tid < 16 * NC;
  float bir = 0, biz = 0, bin = 0, bhr = 0, bhz = 0, bhn = 0;
  if (isg) {
    bir = bih[cb + gc];        bhr = bhh[cb + gc];
    biz = bih[1024 + cb + gc]; bhz = bhh[1024 + cb + gc];
    bin = bih[2048 + cb + gc]; bhn = bhh[2048 + cb + gc];
  }
  __syncthreads();

  const short* w0 = wlds + (0 * NC + c) * WS;
  const short* w1 = wlds + (1 * NC + c) * WS;
  const short* w2 = wlds + (2 * NC + c) * WS;

  float hp = 0.f;

  for (int t = 0; t < T_; ++t) {
    floatx4 ar = {0.f, 0.f, 0.f, 0.f};
    floatx4 az = ar, anh = ar, anx = ar;

    if constexpr (L == 0) {
      // ---- x-part first (always ready) ----
#pragma unroll
      for (int j = 0; j < 2; ++j) {
        const int kt = w * 2 + j;
        const float* xs = x + (long)lr * 262144 + (long)t * 256 + kt * 32 + lq * 8;
        float4 a = *(const float4*)xs;
        float4 b = *(const float4*)(xs + 4);
        U16 u;
        u.d[0] = pkbf(a.x, a.y); u.d[1] = pkbf(a.z, a.w);
        u.d[2] = pkbf(b.x, b.y); u.d[3] = pkbf(b.z, b.w);
        const int ko = 1024 + kt * 32 + lq * 8;
        ar  = MFMA(u.v, *(const shortx8*)(w0 + ko), ar,  0, 0, 0);
        az  = MFMA(u.v, *(const shortx8*)(w1 + ko), az,  0, 0, 0);
        anx = MFMA(u.v, *(const shortx8*)(w2 + ko), anx, 0, 0, 0);
      }
      if (t > 0) {
        // ---- thin poll: 1 u64/lane, write-once line, backoff ----
        const u64* fp = f0 + ((long)(t - 1) * 64 + (w * 16 + lr)) * 8 + lq;
        for (;;) {
          u64 fl = lda(fp);
          if (__all(fl != 0)) break;
          __builtin_amdgcn_s_sleep(1);
        }
        // ---- data read exactly once ----
        const u64* base = y0buf + ((long)(t - 1) * 16 + lr) * 256 + w * 64 + lq * 2;
        u64 q[16];
#pragma unroll
        for (int j = 0; j < 8; ++j) {
          q[2 * j]     = lda(base + j * 8);
          q[2 * j + 1] = lda(base + j * 8 + 1);
        }
#pragma unroll
        for (int j = 0; j < 8; ++j) {
          U16 u; u.q[0] = q[2 * j]; u.q[1] = q[2 * j + 1];
          const int ko = (w * 8 + j) * 32 + lq * 8;
          ar  = MFMA(u.v, *(const shortx8*)(w0 + ko), ar,  0, 0, 0);
          az  = MFMA(u.v, *(const shortx8*)(w1 + ko), az,  0, 0, 0);
          anh = MFMA(u.v, *(const shortx8*)(w2 + ko), anh, 0, 0, 0);
        }
      }
    } else {
      // ---- thin poll for y0[t] and h1[t-1] together ----
      const u64* fpy = f0 + ((long)t * 64 + (w * 16 + lr)) * 8 + lq;
      const u64* fph = f1 + ((long)(t > 0 ? t - 1 : 0) * 128 + (w * 32 + (l & 31))) * 8 + (l >> 5);
      for (;;) {
        u64 fy = lda(fpy);
        u64 fh = (t > 0) ? lda(fph) : 1ull;
        if (__all(fy != 0 && fh != 0)) break;
        __builtin_amdgcn_s_sleep(1);
      }
      // ---- data reads (both batches in flight together) ----
      const u64* yb = y0buf + ((long)t * 16 + lr) * 256 + w * 64 + lq * 2;
      u64 qy[16], qh[16];
#pragma unroll
      for (int j = 0; j < 8; ++j) {
        qy[2 * j]     = lda(yb + j * 8);
        qy[2 * j + 1] = lda(yb + j * 8 + 1);
      }
      if (t > 0) {
        const u64* hb = h1ring + ((long)((t - 1) & 7) * 16 + lr) * 256 + w * 64 + lq * 2;
#pragma unroll
        for (int j = 0; j < 8; ++j) {
          qh[2 * j]     = lda(hb + j * 8);
          qh[2 * j + 1] = lda(hb + j * 8 + 1);
        }
      }
#pragma unroll
      for (int j = 0; j < 8; ++j) {
        U16 u; u.q[0] = qy[2 * j]; u.q[1] = qy[2 * j + 1];
        const int ko = 1024 + (w * 8 + j) * 32 + lq * 8;
        ar  = MFMA(u.v, *(const shortx8*)(w0 + ko), ar,  0, 0, 0);
        az  = MFMA(u.v, *(const shortx8*)(w1 + ko), az,  0, 0, 0);
        anx = MFMA(u.v, *(const shortx8*)(w2 + ko), anx, 0, 0, 0);
      }
      if (t > 0) {
#pragma unroll
        for (int j = 0; j < 8; ++j) {
          U16 u; u.q[0] = qh[2 * j]; u.q[1] = qh[2 * j + 1];
          const int ko = (w * 8 + j) * 32 + lq * 8;
          ar  = MFMA(u.v, *(const shortx8*)(w0 + ko), ar,  0, 0, 0);
          az  = MFMA(u.v, *(const shortx8*)(w1 + ko), az,  0, 0, 0);
          anh = MFMA(u.v, *(const shortx8*)(w2 + ko), anh, 0, 0, 0);
        }
      }
    }

    // ---- cross-wave combine (double-buffered partials, one barrier) ----
    const int par = t & 1;
    if (L == 0 || lr < 8) {
#pragma unroll
      for (int r4 = 0; r4 < 4; ++r4) {
        const int b = lq * 4 + r4;          // row = batch (m89 C/D layout)
        part[par][w][0][b][lr] = ar[r4];
        part[par][w][1][b][lr] = az[r4];
        part[par][w][2][b][lr] = anh[r4];
        part[par][w][3][b][lr] = anx[r4];
      }
    }
    __syncthreads();

    if (isg) {
      float sr = 0, sz = 0, snh = 0, snx = 0;
#pragma unroll
      for (int ww = 0; ww < 4; ++ww) {
        sr  += part[par][ww][0][gb][gc];
        sz  += part[par][ww][1][gb][gc];
        snh += part[par][ww][2][gb][gc];
        snx += part[par][ww][3][gb][gc];
      }
      float r = 1.f / (1.f + __expf(-(sr + bir + bhr)));
      float z = 1.f / (1.f + __expf(-(sz + biz + bhz)));
      float targ = snx + bin + r * (snh + bhn);
      float e2 = __expf(2.f * targ);
      float n = 1.f - 2.f / (e2 + 1.f);       // tanh
      float hn = (1.f - z) * n + z * hp;
      hp = hn;

      unsigned hv = f2bf(hn);
      unsigned v1 = (unsigned)__shfl_down((int)hv, 1);
      unsigned v2 = (unsigned)__shfl_down((int)hv, 2);
      unsigned v3 = (unsigned)__shfl_down((int)hv, 3);

      if constexpr (L == 0) {
        // ring stores -> vmcnt(0) -> flag; dout only at t end
        if ((gc & 3) == 0) {
          u64 word = (u64)(hv | (v1 << 16)) | ((u64)(v2 | (v3 << 16)) << 32);
          sta(y0buf + ((long)t * 16 + gb) * 256 + ((cb + gc) >> 2), word);
        }
        asm volatile("s_waitcnt vmcnt(0)" ::: "memory");
        if (l == 0)
          sta(f0 + ((long)t * 64 + lb) * 8 + w, 1ull);
        if (t == T_ - 1)
          dout[16777216L + (long)gb * 1024 + cb + gc] = hn;
      } else {
        if ((gc & 3) == 0) {
          u64 word = (u64)(hv | (v1 << 16)) | ((u64)(v2 | (v3 << 16)) << 32);
          sta(h1ring + ((long)(t & 7) * 16 + gb) * 256 + ((cb + gc) >> 2), word);
        }
        asm volatile("s_waitcnt vmcnt(0)" ::: "memory");
        if (l == 0)
          sta(f1 + ((long)t * 128 + lb) * 8 + w, 1ull);
        // fp32 output, fire-and-forget (after the flag -> off critical path)
        unsigned fv = __float_as_uint(hn);
        unsigned fw2 = (unsigned)__shfl_down((int)fv, 1);
        if ((gc & 1) == 0)
          *(u64*)(dout + (long)gb * 1048576 + (long)t * 1024 + cb + gc) =
              (u64)fv | ((u64)fw2 << 32);
        if (t == T_ - 1)
          dout[16777216L + 16384 + (long)gb * 1024 + cb + gc] = hn;
      }
    }
  }
}

__global__ __launch_bounds__(256, 1) void gru_kernel(
    const float* __restrict__ x,
    const float* __restrict__ whh0, const float* __restrict__ wih0,
    const float* __restrict__ bih0, const float* __restrict__ bhh0,
    const float* __restrict__ whh1, const float* __restrict__ wih1,
    const float* __restrict__ bih1, const float* __restrict__ bhh1,
    u64* y0buf, u64* h1ring, u64* f0, u64* f1, float* dout)
{
  __shared__ __align__(16) short wlds[48 * 1288];       // 123,648 B (L1 uses 24*2056)
  __shared__ float part[2][4][4][16][17];               //  34,816 B
  const int bid = blockIdx.x, tid = threadIdx.x;
  if (bid < 64)
    gru_wave<0>(bid, tid, x, whh0, wih0, bih0, bhh0, y0buf, h1ring, f0, f1, dout, wlds, part);
  else
    gru_wave<1>(bid - 64, tid, x, whh1, wih1, bih1, bhh1, y0buf, h1ring, f0, f1, dout, wlds, part);
}

extern "C" void kernel_launch(void* const* d_in, const int* in_sizes, int n_in,
                              void* d_out, int out_size, void* d_ws, size_t ws_size,
                              hipStream_t stream) {
  (void)in_sizes; (void)n_in; (void)out_size; (void)ws_size;
  const float* x    = (const float*)d_in[0];
  const float* wih0 = (const float*)d_in[2];
  const float* whh0 = (const float*)d_in[3];
  const float* bih0 = (const float*)d_in[4];
  const float* bhh0 = (const float*)d_in[5];
  const float* wih1 = (const float*)d_in[6];
  const float* whh1 = (const float*)d_in[7];
  const float* bih1 = (const float*)d_in[8];
  const float* bhh1 = (const float*)d_in[9];
  char* ws = (char*)d_ws;
  u64* y0buf  = (u64*)(ws + 0L);          // 33,554,432 B (full, write-once per launch)
  u64* h1ring = (u64*)(ws + 33554432L);   //    262,144 B (8 slots, drift<=1)
  u64* f0     = (u64*)(ws + 33816576L);   //  4,194,304 B write-once flags (zeroed by prep)
  u64* f1     = (u64*)(ws + 38010880L);   //  8,388,608 B write-once flags (zeroed by prep)
  float* out  = (float*)d_out;

  prep_kernel<<<3072, 256, 0, stream>>>((uint4*)f0);   // zeroes f0 then f1 (contiguous)
  gru_kernel<<<192, 256, 0, stream>>>(x, whh0, wih0, bih0, bhh0,
                                      whh1, wih1, bih1, bhh1,
                                      y0buf, h1ring, f0, f1, out);
}